// Round 4
// baseline (271.349 us; speedup 1.0000x reference)
//
#include <hip/hip_runtime.h>
#include <cstdint>
#include <cstddef>

#define BB   32
#define NN   1024
#define FIN  128
#define FOUT 128

typedef __attribute__((ext_vector_type(8))) short bf16x8;
typedef __attribute__((ext_vector_type(4))) float f32x4;

__device__ __forceinline__ unsigned int f2bf(float f) {
    union { float f; unsigned int u; } v; v.f = f;
    unsigned int u = v.u;
    return (u + 0x7FFFu + ((u >> 16) & 1u)) >> 16;   // RNE fp32 -> bf16
}
__device__ __forceinline__ unsigned int pack2(float a, float b) {
    return f2bf(a) | (f2bf(b) << 16);
}

// ---------------------------------------------------------------------------
// Kernel 1: Yt[b][o][m] = sum_f node[b][m][f] * W[o][f]  (bf16, [B][FOUT][NN])
// grid 512 = 32 b x 16 m-tiles(64); block 256. LDS-staged, small & fast.
// ---------------------------------------------------------------------------
__global__ __launch_bounds__(256) void y_kernel(const float* __restrict__ node,
                                                const float* __restrict__ W,
                                                unsigned short* __restrict__ Yt) {
    __shared__ unsigned short Wlds[128 * 136];
    __shared__ unsigned short Nlds[64 * 136];

    const int tid = threadIdx.x;
    const int bid = blockIdx.x;
    const int b   = bid >> 4;
    const int m0  = (bid & 15) * 64;

    #pragma unroll
    for (int i = 0; i < 16; ++i) {
        const int idx = i * 256 + tid;
        const int row = idx >> 5;
        const int c   = (idx & 31) * 4;
        float4 v = ((const float4*)W)[idx];
        uint2 p; p.x = pack2(v.x, v.y); p.y = pack2(v.z, v.w);
        *(uint2*)&Wlds[row * 136 + c] = p;
    }
    {
        const float* base = node + ((size_t)b * NN + m0) * FIN;
        #pragma unroll
        for (int i = 0; i < 8; ++i) {
            const int idx = i * 256 + tid;
            const int row = idx >> 5;
            const int c   = (idx & 31) * 4;
            float4 v = *(const float4*)(base + row * FIN + c);
            uint2 p; p.x = pack2(v.x, v.y); p.y = pack2(v.z, v.w);
            *(uint2*)&Nlds[row * 136 + c] = p;
        }
    }
    __syncthreads();

    const int w = tid >> 6, lane = tid & 63;
    const int wo = w * 32;
    const int lcol = lane & 15, lk = (lane >> 4) * 8;

    f32x4 acc[2][4] = {};
    #pragma unroll
    for (int kc = 0; kc < 4; ++kc) {
        const int kof = kc * 32 + lk;
        bf16x8 a[2], bb[4];
        #pragma unroll
        for (int mi = 0; mi < 2; ++mi)
            a[mi] = *(const bf16x8*)&Wlds[(wo + mi*16 + lcol) * 136 + kof];
        #pragma unroll
        for (int ni = 0; ni < 4; ++ni)
            bb[ni] = *(const bf16x8*)&Nlds[(ni*16 + lcol) * 136 + kof];
        #pragma unroll
        for (int mi = 0; mi < 2; ++mi)
            #pragma unroll
            for (int ni = 0; ni < 4; ++ni)
                acc[mi][ni] = __builtin_amdgcn_mfma_f32_16x16x32_bf16(
                    a[mi], bb[ni], acc[mi][ni], 0, 0, 0);
    }
    __syncthreads();

    unsigned short* Ylds = Wlds;
    const int rq = (lane >> 4) * 4;
    #pragma unroll
    for (int mi = 0; mi < 2; ++mi)
        #pragma unroll
        for (int ni = 0; ni < 4; ++ni)
            #pragma unroll
            for (int r = 0; r < 4; ++r) {
                const int o = wo + mi * 16 + rq + r;
                const int m = ni * 16 + lcol;
                Ylds[o * 72 + m] = (unsigned short)f2bf(acc[mi][ni][r]);
            }
    __syncthreads();

    {
        const int oq = tid >> 3, c = (tid & 7) * 8;
        #pragma unroll
        for (int j = 0; j < 4; ++j) {
            const int o = oq + 32 * j;
            uint4 v = *(const uint4*)&Ylds[o * 72 + c];
            *(uint4*)(Yt + ((size_t)b * FOUT + o) * NN + m0 + c) = v;
        }
    }
}

// ---------------------------------------------------------------------------
// Kernel 2: out = leaky( (adj @ Yt^T) / rowsum(adj) + bias )
// ZERO LDS, ZERO barriers: each wave loads its MFMA fragments directly from
// global (adj rows and Yt rows are both k-contiguous), packs fp32->bf16 in
// VGPRs (rowsum fused), accumulates 16 K-steps, reduces rowsum by shuffle.
// Duplicate fragment reads across waves hit L1/L2; unique HBM = adj once.
// grid 1024 = 32 b x 32 n-tiles(32); block 256 (4 waves: 2x2 over 32n x 128o).
// ---------------------------------------------------------------------------
__global__ __launch_bounds__(256, 4) void gcn_kernel(const float* __restrict__ adj,
                                                     const unsigned short* __restrict__ Yt,
                                                     const float* __restrict__ bias,
                                                     float* __restrict__ out) {
    const int tid  = threadIdx.x;
    const int lane = tid & 63;
    const int w    = tid >> 6;
    const int bid  = blockIdx.x;
    const int b    = bid >> 5;
    const int n0   = (bid & 31) * 32;

    const int lcol = lane & 15;          // fragment row selector / C col
    const int q    = lane >> 4;          // k-octet selector
    const int wm   = (w & 1) * 16;       // n-offset of this wave
    const int wn   = (w >> 1) * 64;      // o-offset of this wave

    const float* aRow = adj + ((size_t)(b * NN + n0 + wm + lcol)) * NN + q * 8;
    const unsigned short* bRow[4];
    #pragma unroll
    for (int ni = 0; ni < 4; ++ni)
        bRow[ni] = Yt + ((size_t)(b * FOUT + wn + ni * 16 + lcol)) * NN + q * 8;

    float bcol[4];
    #pragma unroll
    for (int ni = 0; ni < 4; ++ni) bcol[ni] = bias[wn + ni * 16 + lcol];

    f32x4 acc[4] = {};
    float rsum = 0.f;

    #pragma unroll 4
    for (int s = 0; s < 16; ++s) {
        const int k0 = s * 64;
        // A: this lane's 8 fp32 for kc=0 and kc=1 (k = kc*32 + q*8 .. +7)
        float4 a00 = *(const float4*)(aRow + k0);
        float4 a01 = *(const float4*)(aRow + k0 + 4);
        float4 a10 = *(const float4*)(aRow + k0 + 32);
        float4 a11 = *(const float4*)(aRow + k0 + 36);
        // B: bf16x8 per (kc, ni), already in fragment form
        uint4 b0[4], b1[4];
        #pragma unroll
        for (int ni = 0; ni < 4; ++ni) {
            b0[ni] = *(const uint4*)(bRow[ni] + k0);
            b1[ni] = *(const uint4*)(bRow[ni] + k0 + 32);
        }

        rsum += ((a00.x + a00.y) + (a00.z + a00.w)) + ((a01.x + a01.y) + (a01.z + a01.w));
        rsum += ((a10.x + a10.y) + (a10.z + a10.w)) + ((a11.x + a11.y) + (a11.z + a11.w));

        uint4 pk0, pk1;
        pk0.x = pack2(a00.x, a00.y); pk0.y = pack2(a00.z, a00.w);
        pk0.z = pack2(a01.x, a01.y); pk0.w = pack2(a01.z, a01.w);
        pk1.x = pack2(a10.x, a10.y); pk1.y = pack2(a10.z, a10.w);
        pk1.z = pack2(a11.x, a11.y); pk1.w = pack2(a11.z, a11.w);
        const bf16x8 af0 = *(const bf16x8*)&pk0;
        const bf16x8 af1 = *(const bf16x8*)&pk1;

        #pragma unroll
        for (int ni = 0; ni < 4; ++ni)
            acc[ni] = __builtin_amdgcn_mfma_f32_16x16x32_bf16(
                af0, *(const bf16x8*)&b0[ni], acc[ni], 0, 0, 0);
        #pragma unroll
        for (int ni = 0; ni < 4; ++ni)
            acc[ni] = __builtin_amdgcn_mfma_f32_16x16x32_bf16(
                af1, *(const bf16x8*)&b1[ni], acc[ni], 0, 0, 0);
    }

    // full rowsum of row (wm+lcol): lanes with equal lcol hold disjoint k-octets
    rsum += __shfl_xor(rsum, 16);
    rsum += __shfl_xor(rsum, 32);

    // C/D frag: col = lane&15, row = q*4 + reg. Fetch the needed rows' sums.
    float sc[4];
    #pragma unroll
    for (int r = 0; r < 4; ++r) sc[r] = 1.0f / __shfl(rsum, q * 4 + r);

    float* outB = out + ((size_t)(b * NN + n0 + wm)) * FOUT + wn;
    #pragma unroll
    for (int ni = 0; ni < 4; ++ni) {
        #pragma unroll
        for (int r = 0; r < 4; ++r) {
            float v = acc[ni][r] * sc[r] + bcol[ni];
            v = (v >= 0.f) ? v : 0.01f * v;
            outB[(size_t)(q * 4 + r) * FOUT + ni * 16 + lcol] = v;
        }
    }
}

extern "C" void kernel_launch(void* const* d_in, const int* in_sizes, int n_in,
                              void* d_out, int out_size, void* d_ws, size_t ws_size,
                              hipStream_t stream) {
    const float* node = (const float*)d_in[0];   // [32,1024,128]
    const float* adj  = (const float*)d_in[1];   // [32,1024,1024]
    const float* W    = (const float*)d_in[2];   // [128,128]
    const float* bias = (const float*)d_in[3];   // [128]
    float* out = (float*)d_out;                  // [32,1024,128] fp32
    unsigned short* Yt = (unsigned short*)d_ws;  // [32,128,1024] bf16 = 8 MiB

    hipLaunchKernelGGL(y_kernel,   dim3(512),  dim3(256), 0, stream, node, W, Yt);
    hipLaunchKernelGGL(gcn_kernel, dim3(1024), dim3(256), 0, stream, adj, Yt, bias, out);
}